// Round 6
// baseline (304.239 us; speedup 1.0000x reference)
//
#include <hip/hip_runtime.h>
#include <math.h>

#define NPTS   4096   // points per set (n == m)
#define NPROJ  2000   // projections
#define NB     512    // threads per block (8 waves)
#define NMERGE 8192   // n + m
#define VPT    16     // values per thread (in registers)

// XOR-rotate swizzle: element-within-chunk rotated by chunk index (chunk = i>>5).
__device__ __forceinline__ int sw(int i) {
    return (i & ~31) | ((i + (i >> 5)) & 31);
}

// Bitonic local merge of 16 in-register elements, steps j=8..1, uniform direction.
__device__ __forceinline__ void local_merge(float v[VPT], bool asc) {
    #pragma unroll
    for (int j = 8; j >= 1; j >>= 1) {
        #pragma unroll
        for (int e = 0; e < VPT; ++e) {
            if ((e & j) == 0) {
                float a = v[e], b = v[e | j];
                float mn = fminf(a, b), mx = fmaxf(a, b);
                v[e]     = asc ? mn : mx;
                v[e | j] = asc ? mx : mn;
            }
        }
    }
}

// NB=512/VPT=16 (R5): 48 VGPR, no spill, occ 41%, VALUBusy 82% -> kernel is
// VALU-issue-bound. R6: the 12-iteration bisection tail (each iter = block
// scan + reduce + barrier) is replaced by an LDS histogram over levels +
// one prefix scan, using the identity
//   w1 = (1/4096) * sum_{k in [cmn,cmx)} (T[k] < 0.5 ? T[k] : G - T[k])
// where T = cumsum of per-level delta mass, G = total. Median-free, local.
__global__ __launch_bounds__(NB) void swd_kernel(
    const float* __restrict__ Xs, const float* __restrict__ Xt,
    const float* __restrict__ Us, float* __restrict__ out)
{
    // keys: sorted u || sorted v (swizzled addressing). Exactly 32 KiB.
    // After the merge-path phase keys is dead and is reused:
    //   keys[0..R-1]          : level histogram, then in-place prefix sums
    //                           (R <= 4097: walk to +a and -b needs 2a+2b <= 8192)
    //   ired = keys+4104      : 16 ints, block min/max of level c
    //   red  = keys+4120      : 8 floats, wave partials
    __shared__ float keys[NMERGE];

    const int tid  = threadIdx.x;
    const int arr  = tid >> 8;       // 0 = Xs half, 1 = Xt half
    const int c    = tid & 255;      // chunk index within this array (16 elems/chunk)
    const int lane = tid & 63;
    const int wid  = tid >> 6;       // 0..7
    const int p    = blockIdx.x;

    const float u00 = Us[p*6+0], u01 = Us[p*6+1];
    const float u10 = Us[p*6+2], u11 = Us[p*6+3];
    const float u20 = Us[p*6+4], u21 = Us[p*6+5];

    const float pi_f   = 3.14159265358979323846f;
    const float inv2pi = 0.15915494309189535f;

    const float* __restrict__ X = arr ? Xt : Xs;

    // ---- angles into registers (atan2 is scale-invariant; F.normalize skipped) ----
    float v[VPT];
    {
        const float4* X4 = (const float4*)(X + c * (VPT * 3));  // 48 floats, 16B aligned
        #pragma unroll
        for (int t = 0; t < 4; ++t) {
            float4 q0 = X4[t*3+0], q1 = X4[t*3+1], q2 = X4[t*3+2];
            #define ANG(x,y,z) ((atan2f(-((x)*u01+(y)*u11+(z)*u21), \
                                        -((x)*u00+(y)*u10+(z)*u20)) + pi_f) * inv2pi)
            v[t*4+0] = ANG(q0.x, q0.y, q0.z);
            v[t*4+1] = ANG(q0.w, q1.x, q1.y);
            v[t*4+2] = ANG(q1.z, q1.w, q2.x);
            v[t*4+3] = ANG(q2.y, q2.z, q2.w);
            #undef ANG
        }
    }

    // ---- phases k=2..8: intra-thread, compile-time directions ----
    #pragma unroll
    for (int k = 2; k <= 8; k <<= 1) {
        #pragma unroll
        for (int j = k >> 1; j >= 1; j >>= 1) {
            #pragma unroll
            for (int e = 0; e < VPT; ++e) {
                if ((e & j) == 0) {
                    bool asc = ((e & k) == 0);
                    float a = v[e], b = v[e | j];
                    float mn = fminf(a, b), mx = fmaxf(a, b);
                    v[e]     = asc ? mn : mx;
                    v[e | j] = asc ? mx : mn;
                }
            }
        }
    }

    // ---- phase k=16: fully local, direction uniform per thread ----
    local_merge(v, (c & 1) == 0);

    // ---- phases k=32..1024: within-wave shfl_xor exchanges + local merge ----
    #pragma unroll
    for (int k = 32; k <= 1024; k <<= 1) {
        bool asc = ((c & (k >> 4)) == 0);
        #pragma unroll
        for (int d = k >> 5; d >= 1; d >>= 1) {     // j = k/2 .. 16
            bool keepmin = (((c & d) == 0) == asc);
            #pragma unroll
            for (int e = 0; e < VPT; ++e) {
                float o = __shfl_xor(v[e], d, 64);
                v[e] = keepmin ? fminf(v[e], o) : fmaxf(v[e], o);
            }
        }
        local_merge(v, asc);
    }

    // LDS cross-wave exchange: write all, sync, read partner's 16, minmax, sync.
    #define LDS_XCHG(PXOR, KEEPMIN_EXPR)                                   \
    {                                                                      \
        _Pragma("unroll")                                                  \
        for (int e = 0; e < VPT; ++e) keys[sw(tid * VPT + e)] = v[e];      \
        __syncthreads();                                                   \
        const int pbase = (tid ^ (PXOR)) * VPT;                            \
        const bool keepmin = (KEEPMIN_EXPR);                               \
        _Pragma("unroll")                                                  \
        for (int e = 0; e < VPT; ++e) {                                    \
            float o = keys[sw(pbase + e)];                                 \
            v[e] = keepmin ? fminf(v[e], o) : fmaxf(v[e], o);              \
        }                                                                  \
        __syncthreads();                                                   \
    }

    // ---- phase k=2048: j=1024 crosses waves (c^64), then shfl + local ----
    {
        bool asc = ((c & 128) == 0);
        LDS_XCHG(64, ((c & 64) == 0) == asc);
        #pragma unroll
        for (int d = 32; d >= 1; d >>= 1) {          // j = 512 .. 16
            bool keepmin = (((c & d) == 0) == asc);
            #pragma unroll
            for (int e = 0; e < VPT; ++e) {
                float o = __shfl_xor(v[e], d, 64);
                v[e] = keepmin ? fminf(v[e], o) : fmaxf(v[e], o);
            }
        }
        local_merge(v, asc);
    }

    // ---- phase k=4096 (full ascending merge): j=2048 (c^128), j=1024 (c^64) ----
    LDS_XCHG(128, (c & 128) == 0);
    LDS_XCHG(64,  (c & 64) == 0);
    #pragma unroll
    for (int d = 32; d >= 1; d >>= 1) {              // j = 512 .. 16
        bool keepmin = ((c & d) == 0);
        #pragma unroll
        for (int e = 0; e < VPT; ++e) {
            float o = __shfl_xor(v[e], d, 64);
            v[e] = keepmin ? fminf(v[e], o) : fmaxf(v[e], o);
        }
    }
    local_merge(v, true);
    #undef LDS_XCHG

    // store sorted arrays for the merge
    #pragma unroll
    for (int e = 0; e < VPT; ++e) keys[sw(tid * VPT + e)] = v[e];
    __syncthreads();

    // ---- merge-path merge; keep (delta, c-offset) per element in registers ----
    int c_init;
    int offmin = 32, offmax = -32;                   // per-thread range of c offsets
    unsigned int c8[4] = {0,0,0,0};
    {
        const int d0 = tid * VPT;
        int lo = d0 > NPTS ? d0 - NPTS : 0;
        int hi = d0 < NPTS ? d0 : NPTS;
        while (lo < hi) {                     // ties: u first (stable argsort)
            int mid = (lo + hi) >> 1;
            if (keys[sw(mid)] <= keys[sw(NPTS + (d0 - 1 - mid))]) lo = mid + 1; else hi = mid;
        }
        int i = lo, j = d0 - lo;
        c_init = i - j;
        const float FMAXV = 3.402823466e+38f;
        float cu = (i < NPTS) ? keys[sw(i)] : FMAXV;
        float cv = (j < NPTS) ? keys[sw(NPTS + j)] : FMAXV;
        #pragma unroll
        for (int s = 0; s < VPT; ++s) {
            float cur;
            if (cu <= cv) { cur = cu; ++i; cu = (i < NPTS) ? keys[sw(i)] : FMAXV; }
            else          { cur = cv; ++j; cv = (j < NPTS) ? keys[sw(NPTS + j)] : FMAXV; }
            float nxt = fminf(cu, cv);
            if (nxt == FMAXV) nxt = 1.0f;     // vals_pad appends 1.0
            v[s] = nxt - cur;                 // delta (>= 0)
            int off = (i - j) - c_init;       // in [-16, 16]
            offmin = min(offmin, off);
            offmax = max(offmax, off);
            c8[s >> 2] |= ((unsigned int)(off & 0xff)) << ((s & 3) * 8);
        }
    }

    __syncthreads();   // keys reads done everywhere; safe to reuse keys as scratch
    int*   ired = (int*)(keys + 4104);   // 16 ints (above max histogram index 4096)
    float* red  = keys + 4120;           // 8 floats

    // ---- block min/max of level c ----
    int cmn = c_init + offmin, cmx = c_init + offmax;
    #pragma unroll
    for (int o = 32; o >= 1; o >>= 1) {
        cmn = min(cmn, __shfl_xor(cmn, o, 64));
        cmx = max(cmx, __shfl_xor(cmx, o, 64));
    }
    if (lane == 0) { ired[wid] = cmn; ired[8 + wid] = cmx; }
    __syncthreads();
    {
        int a0 = min(min(ired[0], ired[1]), min(ired[2], ired[3]));
        int a1 = min(min(ired[4], ired[5]), min(ired[6], ired[7]));
        cmn = min(a0, a1);
        int b0 = max(max(ired[8], ired[9]),  max(ired[10], ired[11]));
        int b1 = max(max(ired[12], ired[13]), max(ired[14], ired[15]));
        cmx = max(b0, b1);
    }
    const int R = cmx - cmn + 1;         // number of attained levels, <= 4097

    // ---- histogram: per-level delta mass (ds_add_f32, DS pipe not VALU) ----
    for (int b = tid; b < R; b += NB) keys[b] = 0.0f;
    __syncthreads();
    {
        const int base = c_init - cmn;
        #pragma unroll
        for (int s = 0; s < VPT; ++s) {
            int off = (int)(c8[s >> 2] << ((3 - (s & 3)) * 8)) >> 24;  // sign-extended byte
            atomicAdd(&keys[base + off], v[s]);
        }
    }
    __syncthreads();

    // ---- in-place inclusive prefix scan of keys[0..R-1]; G = grand total ----
    const int nch = (R + NB - 1) / NB;   // usually 1
    float carry = 0.0f;
    for (int ch = 0; ch < nch; ++ch) {
        const int idx = ch * NB + tid;
        float x = (idx < R) ? keys[idx] : 0.0f;
        #pragma unroll
        for (int o = 1; o <= 32; o <<= 1) {           // wave inclusive scan
            float t = __shfl_up(x, o, 64);
            if (lane >= o) x += t;
        }
        if (lane == 63) red[wid] = x;                 // wave totals
        __syncthreads();
        float prefix = carry, ctot = 0.0f;
        #pragma unroll
        for (int w = 0; w < 8; ++w) {
            float rw = red[w];
            prefix += (w < wid) ? rw : 0.0f;
            ctot   += rw;
        }
        x += prefix;
        if (idx < R) keys[idx] = x;
        carry += ctot;
        __syncthreads();                              // red reuse + keys visibility
    }
    const float G = carry;                            // uniform across block

    // ---- w1 = (1/4096) * sum_{k in [cmn,cmx)} (T < 0.5 ? T : G - T) ----
    float f = 0.0f;
    for (int ch = 0; ch < nch; ++ch) {
        const int idx = ch * NB + tid;
        if (idx < R - 1) {                            // exclude last bin (k = cmx)
            float T = keys[idx];
            f += (T < 0.5f) ? T : (G - T);
        }
    }
    #pragma unroll
    for (int o = 32; o >= 1; o >>= 1) f += __shfl_down(f, o, 64);
    if (lane == 0) red[wid] = f;
    __syncthreads();
    if (tid == 0) {
        float w1 = 0.0f;
        #pragma unroll
        for (int w = 0; w < 8; ++w) w1 += red[w];
        w1 *= (1.0f / 4096.0f);
        atomicAdd(out, w1 * (1.0f / (float)NPROJ));
    }
}

extern "C" void kernel_launch(void* const* d_in, const int* in_sizes, int n_in,
                              void* d_out, int out_size, void* d_ws, size_t ws_size,
                              hipStream_t stream) {
    const float* Xs = (const float*)d_in[0];
    const float* Xt = (const float*)d_in[1];
    const float* Us = (const float*)d_in[2];
    float* out = (float*)d_out;

    hipMemsetAsync(out, 0, sizeof(float), stream);
    swd_kernel<<<NPROJ, NB, 0, stream>>>(Xs, Xt, Us, out);
}

// Round 7
// 226.993 us; speedup vs baseline: 1.3403x; 1.3403x over previous
//
#include <hip/hip_runtime.h>
#include <math.h>

#define NPTS   4096   // points per set (n == m)
#define NPROJ  2000   // projections
#define NB     512    // threads per block (8 waves)
#define NMERGE 8192   // n + m
#define VPT    16     // values per thread (in registers)

// XOR-rotate swizzle: element-within-chunk rotated by chunk index (chunk = i>>5).
__device__ __forceinline__ int sw(int i) {
    return (i & ~31) | ((i + (i >> 5)) & 31);
}

// Bitonic local merge of 16 in-register elements, steps j=8..1, uniform direction.
__device__ __forceinline__ void local_merge(float v[VPT], bool asc) {
    #pragma unroll
    for (int j = 8; j >= 1; j >>= 1) {
        #pragma unroll
        for (int e = 0; e < VPT; ++e) {
            if ((e & j) == 0) {
                float a = v[e], b = v[e | j];
                float mn = fminf(a, b), mx = fmaxf(a, b);
                v[e]     = asc ? mn : mx;
                v[e | j] = asc ? mx : mn;
            }
        }
    }
}

// R5 structure (NB=512/VPT=16, 48 VGPR, no spill, VALUBusy 82%) restored after
// R6's LDS-histogram regressed (contended ds_add_f32 on random-walk levels:
// VALU work traded for serialized DS-pipe work, 197->292 us). R7: keep the
// bisection but unpack level offsets once into float registers (ints <= 4100
// are fp32-exact, results bit-identical); each bisection element drops from
// extract+extract+cmp+sel+add to cmp+sel+add, final pass uses free |x| on fma.
__global__ __launch_bounds__(NB) void swd_kernel(
    const float* __restrict__ Xs, const float* __restrict__ Xt,
    const float* __restrict__ Us, float* __restrict__ out)
{
    // keys: sorted u || sorted v (swizzled addressing). Exactly 32 KiB.
    // After the merge-path phase keys is dead; its head is reused:
    //   ired = (int*)keys  [0..15]  : block min/max of level c (8 waves)
    //   red  = keys + 16            : bisection partials (<=15 iters * 8) + final 8
    __shared__ float keys[NMERGE];

    const int tid  = threadIdx.x;
    const int arr  = tid >> 8;       // 0 = Xs half, 1 = Xt half
    const int c    = tid & 255;      // chunk index within this array (16 elems/chunk)
    const int lane = tid & 63;
    const int wid  = tid >> 6;       // 0..7
    const int p    = blockIdx.x;

    const float u00 = Us[p*6+0], u01 = Us[p*6+1];
    const float u10 = Us[p*6+2], u11 = Us[p*6+3];
    const float u20 = Us[p*6+4], u21 = Us[p*6+5];

    const float pi_f   = 3.14159265358979323846f;
    const float inv2pi = 0.15915494309189535f;

    const float* __restrict__ X = arr ? Xt : Xs;

    // ---- angles into registers (atan2 is scale-invariant; F.normalize skipped) ----
    float v[VPT];
    {
        const float4* X4 = (const float4*)(X + c * (VPT * 3));  // 48 floats, 16B aligned
        #pragma unroll
        for (int t = 0; t < 4; ++t) {
            float4 q0 = X4[t*3+0], q1 = X4[t*3+1], q2 = X4[t*3+2];
            #define ANG(x,y,z) ((atan2f(-((x)*u01+(y)*u11+(z)*u21), \
                                        -((x)*u00+(y)*u10+(z)*u20)) + pi_f) * inv2pi)
            v[t*4+0] = ANG(q0.x, q0.y, q0.z);
            v[t*4+1] = ANG(q0.w, q1.x, q1.y);
            v[t*4+2] = ANG(q1.z, q1.w, q2.x);
            v[t*4+3] = ANG(q2.y, q2.z, q2.w);
            #undef ANG
        }
    }

    // ---- phases k=2..8: intra-thread, compile-time directions ----
    #pragma unroll
    for (int k = 2; k <= 8; k <<= 1) {
        #pragma unroll
        for (int j = k >> 1; j >= 1; j >>= 1) {
            #pragma unroll
            for (int e = 0; e < VPT; ++e) {
                if ((e & j) == 0) {
                    bool asc = ((e & k) == 0);
                    float a = v[e], b = v[e | j];
                    float mn = fminf(a, b), mx = fmaxf(a, b);
                    v[e]     = asc ? mn : mx;
                    v[e | j] = asc ? mx : mn;
                }
            }
        }
    }

    // ---- phase k=16: fully local, direction uniform per thread ----
    local_merge(v, (c & 1) == 0);

    // ---- phases k=32..1024: within-wave shfl_xor exchanges + local merge ----
    #pragma unroll
    for (int k = 32; k <= 1024; k <<= 1) {
        bool asc = ((c & (k >> 4)) == 0);
        #pragma unroll
        for (int d = k >> 5; d >= 1; d >>= 1) {     // j = k/2 .. 16
            bool keepmin = (((c & d) == 0) == asc);
            #pragma unroll
            for (int e = 0; e < VPT; ++e) {
                float o = __shfl_xor(v[e], d, 64);
                v[e] = keepmin ? fminf(v[e], o) : fmaxf(v[e], o);
            }
        }
        local_merge(v, asc);
    }

    // LDS cross-wave exchange: write all, sync, read partner's 16, minmax, sync.
    #define LDS_XCHG(PXOR, KEEPMIN_EXPR)                                   \
    {                                                                      \
        _Pragma("unroll")                                                  \
        for (int e = 0; e < VPT; ++e) keys[sw(tid * VPT + e)] = v[e];      \
        __syncthreads();                                                   \
        const int pbase = (tid ^ (PXOR)) * VPT;                            \
        const bool keepmin = (KEEPMIN_EXPR);                               \
        _Pragma("unroll")                                                  \
        for (int e = 0; e < VPT; ++e) {                                    \
            float o = keys[sw(pbase + e)];                                 \
            v[e] = keepmin ? fminf(v[e], o) : fmaxf(v[e], o);              \
        }                                                                  \
        __syncthreads();                                                   \
    }

    // ---- phase k=2048: j=1024 crosses waves (c^64), then shfl + local ----
    {
        bool asc = ((c & 128) == 0);
        LDS_XCHG(64, ((c & 64) == 0) == asc);
        #pragma unroll
        for (int d = 32; d >= 1; d >>= 1) {          // j = 512 .. 16
            bool keepmin = (((c & d) == 0) == asc);
            #pragma unroll
            for (int e = 0; e < VPT; ++e) {
                float o = __shfl_xor(v[e], d, 64);
                v[e] = keepmin ? fminf(v[e], o) : fmaxf(v[e], o);
            }
        }
        local_merge(v, asc);
    }

    // ---- phase k=4096 (full ascending merge): j=2048 (c^128), j=1024 (c^64) ----
    LDS_XCHG(128, (c & 128) == 0);
    LDS_XCHG(64,  (c & 64) == 0);
    #pragma unroll
    for (int d = 32; d >= 1; d >>= 1) {              // j = 512 .. 16
        bool keepmin = ((c & d) == 0);
        #pragma unroll
        for (int e = 0; e < VPT; ++e) {
            float o = __shfl_xor(v[e], d, 64);
            v[e] = keepmin ? fminf(v[e], o) : fmaxf(v[e], o);
        }
    }
    local_merge(v, true);
    #undef LDS_XCHG

    // store sorted arrays for the merge
    #pragma unroll
    for (int e = 0; e < VPT; ++e) keys[sw(tid * VPT + e)] = v[e];
    __syncthreads();

    // ---- merge-path merge; keep (delta, c-offset) per element in registers ----
    // Level after merged element = (#u taken) - (#v taken); cdf value = c/4096 exact.
    // delta -> v[s]; level offset (int in [-16,16]) -> offf[s] as float (exact).
    int c_init;
    int offmin = 32, offmax = -32;                   // per-thread range of c offsets
    float offf[VPT];
    {
        const int d0 = tid * VPT;
        int lo = d0 > NPTS ? d0 - NPTS : 0;
        int hi = d0 < NPTS ? d0 : NPTS;
        while (lo < hi) {                     // ties: u first (stable argsort)
            int mid = (lo + hi) >> 1;
            if (keys[sw(mid)] <= keys[sw(NPTS + (d0 - 1 - mid))]) lo = mid + 1; else hi = mid;
        }
        int i = lo, j = d0 - lo;
        c_init = i - j;
        const float FMAXV = 3.402823466e+38f;
        float cu = (i < NPTS) ? keys[sw(i)] : FMAXV;
        float cv = (j < NPTS) ? keys[sw(NPTS + j)] : FMAXV;
        #pragma unroll
        for (int s = 0; s < VPT; ++s) {
            float cur;
            if (cu <= cv) { cur = cu; ++i; cu = (i < NPTS) ? keys[sw(i)] : FMAXV; }
            else          { cur = cv; ++j; cv = (j < NPTS) ? keys[sw(NPTS + j)] : FMAXV; }
            float nxt = fminf(cu, cv);
            if (nxt == FMAXV) nxt = 1.0f;     // vals_pad appends 1.0
            v[s] = nxt - cur;                 // delta (>= 0)
            int off = (i - j) - c_init;       // in [-16, 16]
            offmin = min(offmin, off);
            offmax = max(offmax, off);
            offf[s] = (float)off;
        }
    }

    __syncthreads();   // keys reads done everywhere; safe to reuse keys as scratch
    int*   ired = (int*)keys;       // keys[0..15]
    float* red  = keys + 16;        // keys[16..]

    // ---- block min/max of level c: narrows the bisection to the attained range ----
    int cmn = c_init + offmin, cmx = c_init + offmax;
    #pragma unroll
    for (int o = 32; o >= 1; o >>= 1) {
        cmn = min(cmn, __shfl_xor(cmn, o, 64));
        cmx = max(cmx, __shfl_xor(cmx, o, 64));
    }
    if (lane == 0) { ired[wid] = cmn; ired[8 + wid] = cmx; }
    __syncthreads();
    {
        int a0 = min(min(ired[0], ired[1]), min(ired[2], ired[3]));
        int a1 = min(min(ired[4], ired[5]), min(ired[6], ired[7]));
        cmn = min(a0, a1);
        int b0 = max(max(ired[8], ired[9]),  max(ired[10], ired[11]));
        int b1 = max(max(ired[12], ired[13]), max(ired[14], ired[15]));
        cmx = max(b0, b1);
    }

    // ---- level median c* via integer bisection (no histogram, no atomics) ----
    // c* = smallest c with W(<= c) >= 0.5, W = sum of deltas at levels <= c.
    // Invariant: W(<= lo) < 0.5 <= W(<= hi).
    int lo_c = cmn - 1, hi_c = cmx;
    int it = 0;
    #pragma unroll 1
    while (hi_c - lo_c > 1) {
        const int mid = (lo_c + hi_c) >> 1;   // uniform across block
        const float thrf = (float)(mid - c_init);
        float s_loc = 0.0f;
        #pragma unroll
        for (int s = 0; s < VPT; ++s)
            s_loc += (offf[s] <= thrf) ? v[s] : 0.0f;
        #pragma unroll
        for (int o = 32; o >= 1; o >>= 1) s_loc += __shfl_down(s_loc, o, 64);
        if (lane == 0) red[it * 8 + wid] = s_loc;
        __syncthreads();
        float S = 0.0f;
        #pragma unroll
        for (int w = 0; w < 8; ++w) S += red[it * 8 + w];
        if (S >= 0.5f) hi_c = mid; else lo_c = mid;
        ++it;
    }
    const int cstar = hi_c;

    // ---- w1 = (1/4096) * sum delta * |c - c*| (register pass + one reduction) ----
    float part = 0.0f;
    {
        const float thrf = (float)(cstar - c_init);
        #pragma unroll
        for (int s = 0; s < VPT; ++s)
            part += v[s] * fabsf(offf[s] - thrf);   // |x| is a free fma modifier
    }
    #pragma unroll
    for (int o = 32; o >= 1; o >>= 1) part += __shfl_down(part, o, 64);
    if (lane == 0) red[15 * 8 + wid] = part;
    __syncthreads();
    if (tid == 0) {
        float w1 = 0.0f;
        #pragma unroll
        for (int w = 0; w < 8; ++w) w1 += red[15 * 8 + w];
        w1 *= (1.0f / 4096.0f);
        atomicAdd(out, w1 * (1.0f / (float)NPROJ));
    }
}

extern "C" void kernel_launch(void* const* d_in, const int* in_sizes, int n_in,
                              void* d_out, int out_size, void* d_ws, size_t ws_size,
                              hipStream_t stream) {
    const float* Xs = (const float*)d_in[0];
    const float* Xt = (const float*)d_in[1];
    const float* Us = (const float*)d_in[2];
    float* out = (float*)d_out;

    hipMemsetAsync(out, 0, sizeof(float), stream);
    swd_kernel<<<NPROJ, NB, 0, stream>>>(Xs, Xt, Us, out);
}

// Round 8
// 220.888 us; speedup vs baseline: 1.3773x; 1.0276x over previous
//
#include <hip/hip_runtime.h>
#include <math.h>

#define NPTS   4096   // points per set (n == m)
#define NPROJ  2000   // projections
#define NB     512    // threads per block (8 waves)
#define NMERGE 8192   // n + m
#define VPT    16     // values per thread (in registers)

// XOR-rotate swizzle: element-within-chunk rotated by chunk index (chunk = i>>5).
__device__ __forceinline__ int sw(int i) {
    return (i & ~31) | ((i + (i >> 5)) & 31);
}

// Bitonic local merge of 16 in-register elements, steps j=8..1, uniform direction.
__device__ __forceinline__ void local_merge(float v[VPT], bool asc) {
    #pragma unroll
    for (int j = 8; j >= 1; j >>= 1) {
        #pragma unroll
        for (int e = 0; e < VPT; ++e) {
            if ((e & j) == 0) {
                float a = v[e], b = v[e | j];
                float mn = fminf(a, b), mx = fmaxf(a, b);
                v[e]     = asc ? mn : mx;
                v[e | j] = asc ? mx : mn;
            }
        }
    }
}

// R8: bitonic phases k=2048/k=4096 (23 steps, ~1800 VALU/thread, 6 barriers)
// replaced by 2 merge-path rounds (1024+1024 -> 2048 -> 4096) reusing the
// proven u||v merge code shape: bsearch + 16-step serial merge, outputs in
// registers, in-place LDS write after a barrier. Phase k=1024 direction is
// forced ascending (each 1024-block is bitonic there, so an ascending merge
// is legal for every run) so all 8 wave-runs emerge ascending & merge-ready.
// Sorted values identical => downstream bit-identical.
__global__ __launch_bounds__(NB) void swd_kernel(
    const float* __restrict__ Xs, const float* __restrict__ Xt,
    const float* __restrict__ Us, float* __restrict__ out)
{
    // keys: sorted u || sorted v (swizzled addressing). Exactly 32 KiB.
    // After the merge-path phase keys is dead; its head is reused:
    //   ired = (int*)keys  [0..15]  : block min/max of level c (8 waves)
    //   red  = keys + 16            : bisection partials (<=15 iters * 8) + final 8
    __shared__ float keys[NMERGE];

    const int tid  = threadIdx.x;
    const int arr  = tid >> 8;       // 0 = Xs half, 1 = Xt half
    const int c    = tid & 255;      // chunk index within this array (16 elems/chunk)
    const int lane = tid & 63;
    const int wid  = tid >> 6;       // 0..7
    const int p    = blockIdx.x;

    const float u00 = Us[p*6+0], u01 = Us[p*6+1];
    const float u10 = Us[p*6+2], u11 = Us[p*6+3];
    const float u20 = Us[p*6+4], u21 = Us[p*6+5];

    const float pi_f   = 3.14159265358979323846f;
    const float inv2pi = 0.15915494309189535f;

    const float* __restrict__ X = arr ? Xt : Xs;

    // ---- angles into registers (atan2 is scale-invariant; F.normalize skipped) ----
    float v[VPT];
    {
        const float4* X4 = (const float4*)(X + c * (VPT * 3));  // 48 floats, 16B aligned
        #pragma unroll
        for (int t = 0; t < 4; ++t) {
            float4 q0 = X4[t*3+0], q1 = X4[t*3+1], q2 = X4[t*3+2];
            #define ANG(x,y,z) ((atan2f(-((x)*u01+(y)*u11+(z)*u21), \
                                        -((x)*u00+(y)*u10+(z)*u20)) + pi_f) * inv2pi)
            v[t*4+0] = ANG(q0.x, q0.y, q0.z);
            v[t*4+1] = ANG(q0.w, q1.x, q1.y);
            v[t*4+2] = ANG(q1.z, q1.w, q2.x);
            v[t*4+3] = ANG(q2.y, q2.z, q2.w);
            #undef ANG
        }
    }

    // ---- phases k=2..8: intra-thread, compile-time directions ----
    #pragma unroll
    for (int k = 2; k <= 8; k <<= 1) {
        #pragma unroll
        for (int j = k >> 1; j >= 1; j >>= 1) {
            #pragma unroll
            for (int e = 0; e < VPT; ++e) {
                if ((e & j) == 0) {
                    bool asc = ((e & k) == 0);
                    float a = v[e], b = v[e | j];
                    float mn = fminf(a, b), mx = fmaxf(a, b);
                    v[e]     = asc ? mn : mx;
                    v[e | j] = asc ? mx : mn;
                }
            }
        }
    }

    // ---- phase k=16: fully local, direction uniform per thread ----
    local_merge(v, (c & 1) == 0);

    // ---- phases k=32..1024: within-wave shfl_xor exchanges + local merge ----
    // k=1024 forced ascending: each aligned 1024-block is bitonic at that
    // point (asc-512 || desc-512), so an ascending merge is legal for all
    // runs; the merge-path rounds below require ascending runs.
    #pragma unroll
    for (int k = 32; k <= 1024; k <<= 1) {
        bool asc = (k == 1024) || ((c & (k >> 4)) == 0);
        #pragma unroll
        for (int d = k >> 5; d >= 1; d >>= 1) {     // j = k/2 .. 16
            bool keepmin = (((c & d) == 0) == asc);
            #pragma unroll
            for (int e = 0; e < VPT; ++e) {
                float o = __shfl_xor(v[e], d, 64);
                v[e] = keepmin ? fminf(v[e], o) : fmaxf(v[e], o);
            }
        }
        local_merge(v, asc);
    }

    // ---- store the 8 ascending 1024-runs ----
    #pragma unroll
    for (int e = 0; e < VPT; ++e) keys[sw(tid * VPT + e)] = v[e];
    __syncthreads();

    // ---- merge-path rounds: 1024+1024 -> 2048, then 2048+2048 -> 4096 ----
    // Each half (arr) merges independently; thread output base = tid*16
    // (identity: half + cc*16 = Ab + dd). Outputs land in v[], written back
    // in place after a barrier.
    #define MERGE_ROUND(L, AB, DD)                                          \
    {                                                                       \
        const int Ab = (AB);                                                \
        const int Bb = Ab + (L);                                            \
        const int dd = (DD);                                                \
        int lo = dd > (L) ? dd - (L) : 0;                                   \
        int hi = dd < (L) ? dd : (L);                                       \
        while (lo < hi) {                                                   \
            int mid = (lo + hi) >> 1;                                       \
            if (keys[sw(Ab + mid)] <= keys[sw(Bb + (dd - 1 - mid))])        \
                lo = mid + 1; else hi = mid;                                \
        }                                                                   \
        int i = lo, j = dd - lo;                                            \
        const float INFV = __builtin_inff();                                \
        float cu = (i < (L)) ? keys[sw(Ab + i)] : INFV;                     \
        float cv = (j < (L)) ? keys[sw(Bb + j)] : INFV;                     \
        _Pragma("unroll")                                                   \
        for (int s = 0; s < VPT; ++s) {                                     \
            bool take = (cu <= cv);                                         \
            v[s] = fminf(cu, cv);                                           \
            if (take) { ++i; cu = (i < (L)) ? keys[sw(Ab + i)] : INFV; }    \
            else      { ++j; cv = (j < (L)) ? keys[sw(Bb + j)] : INFV; }    \
        }                                                                   \
        __syncthreads();                                                    \
        _Pragma("unroll")                                                   \
        for (int e = 0; e < VPT; ++e) keys[sw(tid * VPT + e)] = v[e];       \
        __syncthreads();                                                    \
    }

    // Round A: L=1024; pair = c>>7 within the half, diagonal = (c&127)*16.
    MERGE_ROUND(1024, arr * 4096 + (c >> 7) * 2048, (c & 127) * VPT)
    // Round B: L=2048; single pair per half, diagonal = c*16.
    MERGE_ROUND(2048, arr * 4096, c * VPT)
    #undef MERGE_ROUND
    // keys now holds: sorted u at [0,4096), sorted v at [4096,8192).

    // ---- merge-path merge; keep (delta, c-offset) per element in registers ----
    // Level after merged element = (#u taken) - (#v taken); cdf value = c/4096 exact.
    // delta -> v[s]; level offset (int in [-16,16]) -> offf[s] as float (exact).
    int c_init;
    int offmin = 32, offmax = -32;                   // per-thread range of c offsets
    float offf[VPT];
    {
        const int d0 = tid * VPT;
        int lo = d0 > NPTS ? d0 - NPTS : 0;
        int hi = d0 < NPTS ? d0 : NPTS;
        while (lo < hi) {                     // ties: u first (stable argsort)
            int mid = (lo + hi) >> 1;
            if (keys[sw(mid)] <= keys[sw(NPTS + (d0 - 1 - mid))]) lo = mid + 1; else hi = mid;
        }
        int i = lo, j = d0 - lo;
        c_init = i - j;
        const float FMAXV = 3.402823466e+38f;
        float cu = (i < NPTS) ? keys[sw(i)] : FMAXV;
        float cv = (j < NPTS) ? keys[sw(NPTS + j)] : FMAXV;
        #pragma unroll
        for (int s = 0; s < VPT; ++s) {
            float cur;
            if (cu <= cv) { cur = cu; ++i; cu = (i < NPTS) ? keys[sw(i)] : FMAXV; }
            else          { cur = cv; ++j; cv = (j < NPTS) ? keys[sw(NPTS + j)] : FMAXV; }
            float nxt = fminf(cu, cv);
            if (nxt == FMAXV) nxt = 1.0f;     // vals_pad appends 1.0
            v[s] = nxt - cur;                 // delta (>= 0)
            int off = (i - j) - c_init;       // in [-16, 16]
            offmin = min(offmin, off);
            offmax = max(offmax, off);
            offf[s] = (float)off;
        }
    }

    __syncthreads();   // keys reads done everywhere; safe to reuse keys as scratch
    int*   ired = (int*)keys;       // keys[0..15]
    float* red  = keys + 16;        // keys[16..]

    // ---- block min/max of level c: narrows the bisection to the attained range ----
    int cmn = c_init + offmin, cmx = c_init + offmax;
    #pragma unroll
    for (int o = 32; o >= 1; o >>= 1) {
        cmn = min(cmn, __shfl_xor(cmn, o, 64));
        cmx = max(cmx, __shfl_xor(cmx, o, 64));
    }
    if (lane == 0) { ired[wid] = cmn; ired[8 + wid] = cmx; }
    __syncthreads();
    {
        int a0 = min(min(ired[0], ired[1]), min(ired[2], ired[3]));
        int a1 = min(min(ired[4], ired[5]), min(ired[6], ired[7]));
        cmn = min(a0, a1);
        int b0 = max(max(ired[8], ired[9]),  max(ired[10], ired[11]));
        int b1 = max(max(ired[12], ired[13]), max(ired[14], ired[15]));
        cmx = max(b0, b1);
    }

    // ---- level median c* via integer bisection (no histogram, no atomics) ----
    // c* = smallest c with W(<= c) >= 0.5, W = sum of deltas at levels <= c.
    // Invariant: W(<= lo) < 0.5 <= W(<= hi).
    int lo_c = cmn - 1, hi_c = cmx;
    int it = 0;
    #pragma unroll 1
    while (hi_c - lo_c > 1) {
        const int mid = (lo_c + hi_c) >> 1;   // uniform across block
        const float thrf = (float)(mid - c_init);
        float s_loc = 0.0f;
        #pragma unroll
        for (int s = 0; s < VPT; ++s)
            s_loc += (offf[s] <= thrf) ? v[s] : 0.0f;
        #pragma unroll
        for (int o = 32; o >= 1; o >>= 1) s_loc += __shfl_down(s_loc, o, 64);
        if (lane == 0) red[it * 8 + wid] = s_loc;
        __syncthreads();
        float S = 0.0f;
        #pragma unroll
        for (int w = 0; w < 8; ++w) S += red[it * 8 + w];
        if (S >= 0.5f) hi_c = mid; else lo_c = mid;
        ++it;
    }
    const int cstar = hi_c;

    // ---- w1 = (1/4096) * sum delta * |c - c*| (register pass + one reduction) ----
    float part = 0.0f;
    {
        const float thrf = (float)(cstar - c_init);
        #pragma unroll
        for (int s = 0; s < VPT; ++s)
            part += v[s] * fabsf(offf[s] - thrf);   // |x| is a free fma modifier
    }
    #pragma unroll
    for (int o = 32; o >= 1; o >>= 1) part += __shfl_down(part, o, 64);
    if (lane == 0) red[15 * 8 + wid] = part;
    __syncthreads();
    if (tid == 0) {
        float w1 = 0.0f;
        #pragma unroll
        for (int w = 0; w < 8; ++w) w1 += red[15 * 8 + w];
        w1 *= (1.0f / 4096.0f);
        atomicAdd(out, w1 * (1.0f / (float)NPROJ));
    }
}

extern "C" void kernel_launch(void* const* d_in, const int* in_sizes, int n_in,
                              void* d_out, int out_size, void* d_ws, size_t ws_size,
                              hipStream_t stream) {
    const float* Xs = (const float*)d_in[0];
    const float* Xt = (const float*)d_in[1];
    const float* Us = (const float*)d_in[2];
    float* out = (float*)d_out;

    hipMemsetAsync(out, 0, sizeof(float), stream);
    swd_kernel<<<NPROJ, NB, 0, stream>>>(Xs, Xt, Us, out);
}